// Round 1
// baseline (853.859 us; speedup 1.0000x reference)
//
#include <hip/hip_runtime.h>

typedef __attribute__((ext_vector_type(8))) short short8v;
typedef __attribute__((ext_vector_type(4))) float floatx4;

#define TK   1024      // tokens = B*T
#define IND  5120      // IN
#define HD   2048
#define OD   2048
#define NE   4

static __device__ __forceinline__ short f2bf(float f) {
    unsigned int u = __builtin_bit_cast(unsigned int, f);
    unsigned int r = (u + 0x7FFFu + ((u >> 16) & 1u)) >> 16;
    return (short)r;
}

// ---------------- pre: conv + residual + RMSNorm + router ----------------
__global__ __launch_bounds__(256)
void pre_kernel(const float* __restrict__ x, const float* __restrict__ conv_w,
                const float* __restrict__ conv_b, const float* __restrict__ rms_w,
                const float* __restrict__ router_w,
                short* __restrict__ nbf, float* __restrict__ combine)
{
    __shared__ float xs[6 * 1280];
    __shared__ float cw[3 * 1280];
    __shared__ float cb[1280];
    __shared__ float red[8];
    __shared__ float rred[16];

    const int t  = blockIdx.x;       // token 0..1023
    const int b  = t >> 8;
    const int tt = t & 255;
    const int s0 = tt * 4;
    const int tid = threadIdx.x;

    for (int idx = tid; idx < 7680; idx += 256) {
        int f = idx / 1280, d = idx - f * 1280;
        int s = s0 - 1 + f;
        float v = 0.f;
        if (s >= 0 && s < 1024) v = x[((size_t)b * 1024 + s) * 1280 + d];
        xs[idx] = v;
    }
    for (int idx = tid; idx < 3840; idx += 256) cw[idx] = conv_w[idx];
    for (int idx = tid; idx < 1280; idx += 256) cb[idx] = conv_b[idx];
    __syncthreads();

    float yv[20];
    float ss = 0.f;
#pragma unroll
    for (int j = 0; j < 20; ++j) {
        int k = tid + j * 256;           // IN index
        int f = k / 1280, d = k - f * 1280;
        float xm = xs[(f + 1) * 1280 + d];
        float y = xm + xs[f * 1280 + d] * cw[d * 3 + 0]
                     + xm               * cw[d * 3 + 1]
                     + xs[(f + 2) * 1280 + d] * cw[d * 3 + 2]
                     + cb[d];
        yv[j] = y;
        ss += y * y;
    }
    const int lane = tid & 63, wid = tid >> 6;
#pragma unroll
    for (int off = 32; off; off >>= 1) ss += __shfl_xor(ss, off);
    if (lane == 0) red[wid] = ss;
    __syncthreads();
    if (tid == 0) {
        float s4 = red[0] + red[1] + red[2] + red[3];
        red[4] = 1.0f / sqrtf(s4 * (1.0f / 5120.f) + 1e-8f);
    }
    __syncthreads();
    const float inv = red[4];

    float r0 = 0.f, r1 = 0.f, r2 = 0.f, r3 = 0.f;
#pragma unroll
    for (int j = 0; j < 20; ++j) {
        int k = tid + j * 256;
        float nv = yv[j] * inv * rms_w[k];
        nbf[(size_t)t * IND + k] = f2bf(nv);
        r0 += nv * router_w[k];
        r1 += nv * router_w[IND + k];
        r2 += nv * router_w[2 * IND + k];
        r3 += nv * router_w[3 * IND + k];
    }
#pragma unroll
    for (int off = 32; off; off >>= 1) {
        r0 += __shfl_xor(r0, off); r1 += __shfl_xor(r1, off);
        r2 += __shfl_xor(r2, off); r3 += __shfl_xor(r3, off);
    }
    if (lane == 0) { rred[wid*4+0]=r0; rred[wid*4+1]=r1; rred[wid*4+2]=r2; rred[wid*4+3]=r3; }
    __syncthreads();
    if (tid == 0) {
        float p[4];
#pragma unroll
        for (int e = 0; e < 4; ++e) {
            float lg = rred[e] + rred[4+e] + rred[8+e] + rred[12+e];
            p[e] = 1.0f / (1.0f + expf(-lg));
        }
        int i1 = 0;
        for (int e = 1; e < 4; ++e) if (p[e] > p[i1]) i1 = e;
        int i2 = (i1 == 0) ? 1 : 0;
        for (int e = 0; e < 4; ++e) if (e != i1 && p[e] > p[i2]) i2 = e;
        float wsum = p[i1] + p[i2] + 1e-6f;
        float c[4] = {0.f, 0.f, 0.f, 0.f};
        c[i1] = p[i1] / wsum;
        c[i2] = p[i2] / wsum;
        combine[t*4+0] = c[0]; combine[t*4+1] = c[1];
        combine[t*4+2] = c[2]; combine[t*4+3] = c[3];
    }
}

// ---------------- fp32 -> bf16 weight conversion ----------------
__global__ __launch_bounds__(256)
void convert_kernel(const float* __restrict__ src, short* __restrict__ dst)
{
    size_t i = ((size_t)blockIdx.x * 256 + threadIdx.x) * 8;
    float4 a = *(const float4*)(src + i);
    float4 b = *(const float4*)(src + i + 4);
    short8v o;
    o[0] = f2bf(a.x); o[1] = f2bf(a.y); o[2] = f2bf(a.z); o[3] = f2bf(a.w);
    o[4] = f2bf(b.x); o[5] = f2bf(b.y); o[6] = f2bf(b.z); o[7] = f2bf(b.w);
    *(short8v*)(dst + i) = o;
}

// ---------------- GEMM (m97-style 128x128, BK=64) ----------------
// MODE 1: h = relu(n @ W1_all^T + b1); routed cols scaled by combine -> bf16
// MODE 2: out = h_scaled @ W2_seg^T + (sb2 + sum_e combine*eb2)      -> fp32
template<int MODE>
__global__ __launch_bounds__(256)
void gemm_kernel(const short* __restrict__ A, const short* __restrict__ Bw,
                 const float* __restrict__ sb1, const float* __restrict__ eb1,
                 const float* __restrict__ combine,
                 short* __restrict__ Hout,
                 const float* __restrict__ sb2, const float* __restrict__ eb2,
                 float* __restrict__ Out)
{
    constexpr int KTOT = (MODE == 1) ? 5120 : 10240;
    constexpr int LDA  = (MODE == 1) ? 5120 : 10240;
    __shared__ short As[128 * 64];
    __shared__ short Bs[128 * 64];
    const int tid  = threadIdx.x;
    const int lane = tid & 63;
    const int wid  = tid >> 6;
    const int wr   = wid >> 1, wc = wid & 1;
    const int m0 = blockIdx.y * 128;
    const int n0 = blockIdx.x * 128;

    floatx4 acc[4][4] = {};

    for (int k0 = 0; k0 < KTOT; k0 += 64) {
#pragma unroll
        for (int i = 0; i < 4; ++i) {
            const int idx = i * 256 + tid;      // 0..1023
            const int row = idx >> 3;
            const int c8  = (idx & 7) * 8;
            const short* ga = A + (size_t)(m0 + row) * LDA + (k0 + c8);
            __builtin_amdgcn_global_load_lds(
                (const __attribute__((address_space(1))) void*)ga,
                (__attribute__((address_space(3))) void*)(As + idx * 8), 16, 0, 0);
            const short* gb;
            if constexpr (MODE == 1) {
                gb = Bw + (size_t)(n0 + row) * 5120 + (k0 + c8);
            } else {
                gb = Bw + ((size_t)(k0 >> 11)) * (2048u * 2048u)
                        + (size_t)(n0 + row) * 2048 + ((k0 & 2047) + c8);
            }
            __builtin_amdgcn_global_load_lds(
                (const __attribute__((address_space(1))) void*)gb,
                (__attribute__((address_space(3))) void*)(Bs + idx * 8), 16, 0, 0);
        }
        __syncthreads();
#pragma unroll
        for (int kk = 0; kk < 2; ++kk) {
            short8v af[4], bfr[4];
            const int kc = kk * 32 + (lane >> 4) * 8;
#pragma unroll
            for (int m = 0; m < 4; ++m) {
                const int r = wr * 64 + m * 16 + (lane & 15);
                af[m] = *(const short8v*)(As + r * 64 + kc);
            }
#pragma unroll
            for (int n = 0; n < 4; ++n) {
                const int r = wc * 64 + n * 16 + (lane & 15);
                bfr[n] = *(const short8v*)(Bs + r * 64 + kc);
            }
#pragma unroll
            for (int m = 0; m < 4; ++m)
#pragma unroll
                for (int n = 0; n < 4; ++n)
                    acc[m][n] = __builtin_amdgcn_mfma_f32_16x16x32_bf16(
                        af[m], bfr[n], acc[m][n], 0, 0, 0);
        }
        __syncthreads();
    }

#pragma unroll
    for (int m = 0; m < 4; ++m) {
        const int rb = m0 + wr * 64 + m * 16 + ((lane >> 4) * 4);
#pragma unroll
        for (int n = 0; n < 4; ++n) {
            const int col = n0 + wc * 64 + n * 16 + (lane & 15);
#pragma unroll
            for (int r = 0; r < 4; ++r) {
                const int rowg = rb + r;
                float v = acc[m][n][r];
                if constexpr (MODE == 1) {
                    v += (col < 2048) ? sb1[col] : eb1[col - 2048];
                    v = fmaxf(v, 0.0f);
                    if (col >= 2048) v *= combine[rowg * 4 + ((col - 2048) >> 11)];
                    Hout[(size_t)rowg * 10240 + col] = f2bf(v);
                } else {
                    float b2 = sb2[col];
#pragma unroll
                    for (int e = 0; e < 4; ++e)
                        b2 += combine[rowg * 4 + e] * eb2[e * 2048 + col];
                    Out[(size_t)rowg * 2048 + col] = v + b2;
                }
            }
        }
    }
}

extern "C" void kernel_launch(void* const* d_in, const int* in_sizes, int n_in,
                              void* d_out, int out_size, void* d_ws, size_t ws_size,
                              hipStream_t stream)
{
    const float* x        = (const float*)d_in[0];
    const float* conv_w   = (const float*)d_in[1];
    const float* conv_b   = (const float*)d_in[2];
    const float* rms_w    = (const float*)d_in[3];
    const float* router_w = (const float*)d_in[4];
    const float* sw1      = (const float*)d_in[5];
    const float* sb1      = (const float*)d_in[6];
    const float* sw2      = (const float*)d_in[7];
    const float* sb2      = (const float*)d_in[8];
    const float* ew1      = (const float*)d_in[9];
    const float* eb1      = (const float*)d_in[10];
    const float* ew2      = (const float*)d_in[11];
    const float* eb2      = (const float*)d_in[12];
    float* out = (float*)d_out;

    char* ws = (char*)d_ws;
    short* nbf     = (short*)(ws);                    // 1024*5120*2   = 10,485,760
    short* hbf     = (short*)(ws + 10485760);         // 1024*10240*2  = 20,971,520
    short* w1b     = (short*)(ws + 31457280);         // 10240*5120*2  = 104,857,600
    short* w2b     = (short*)(ws + 136314880);        // 2048*10240*2  = 41,943,040
    float* combine = (float*)(ws + 178257920);        // 1024*4*4      = 16,384

    pre_kernel<<<1024, 256, 0, stream>>>(x, conv_w, conv_b, rms_w, router_w, nbf, combine);

    convert_kernel<<<5120,  256, 0, stream>>>(sw1, w1b);
    convert_kernel<<<20480, 256, 0, stream>>>(ew1, w1b + (size_t)2048 * 5120);
    convert_kernel<<<2048,  256, 0, stream>>>(sw2, w2b);
    convert_kernel<<<8192,  256, 0, stream>>>(ew2, w2b + (size_t)2048 * 2048);

    gemm_kernel<1><<<dim3(80, 8), 256, 0, stream>>>(
        nbf, w1b, sb1, eb1, combine, hbf, nullptr, nullptr, nullptr);
    gemm_kernel<2><<<dim3(16, 8), 256, 0, stream>>>(
        hbf, w2b, nullptr, nullptr, combine, nullptr, sb2, eb2, out);
}

// Round 2
// 595.368 us; speedup vs baseline: 1.4342x; 1.4342x over previous
//
#include <hip/hip_runtime.h>

typedef __attribute__((ext_vector_type(8))) short short8v;
typedef __attribute__((ext_vector_type(4))) float floatx4;

#define IND 5120

static __device__ __forceinline__ short f2bf(float f) {
    unsigned int u = __builtin_bit_cast(unsigned int, f);
    unsigned int r = (u + 0x7FFFu + ((u >> 16) & 1u)) >> 16;
    return (short)r;
}

// ---------------- pre: conv + residual + RMSNorm + router ----------------
// Writes n in tile-native swizzled bf16 layout: tiles of [128 rows][64 cols],
// short index within tile = (row&127)*64 + ((col&63) ^ ((row&7)<<3)).
__global__ __launch_bounds__(256)
void pre_kernel(const float* __restrict__ x, const float* __restrict__ conv_w,
                const float* __restrict__ conv_b, const float* __restrict__ rms_w,
                const float* __restrict__ router_w,
                short* __restrict__ nbf, float* __restrict__ combine)
{
    __shared__ float xs[6 * 1280];
    __shared__ float cw[3 * 1280];
    __shared__ float cb[1280];
    __shared__ float red[8];
    __shared__ float rred[16];

    const int t  = blockIdx.x;       // token 0..1023
    const int b  = t >> 8;
    const int tt = t & 255;
    const int s0 = tt * 4;
    const int tid = threadIdx.x;

    for (int idx = tid; idx < 7680; idx += 256) {
        int f = idx / 1280, d = idx - f * 1280;
        int s = s0 - 1 + f;
        float v = 0.f;
        if (s >= 0 && s < 1024) v = x[((size_t)b * 1024 + s) * 1280 + d];
        xs[idx] = v;
    }
    for (int idx = tid; idx < 3840; idx += 256) cw[idx] = conv_w[idx];
    for (int idx = tid; idx < 1280; idx += 256) cb[idx] = conv_b[idx];
    __syncthreads();

    float yv[20];
    float ss = 0.f;
#pragma unroll
    for (int j = 0; j < 20; ++j) {
        int k = tid + j * 256;           // IN index
        int f = k / 1280, d = k - f * 1280;
        float xm = xs[(f + 1) * 1280 + d];
        float y = xm + xs[f * 1280 + d] * cw[d * 3 + 0]
                     + xm               * cw[d * 3 + 1]
                     + xs[(f + 2) * 1280 + d] * cw[d * 3 + 2]
                     + cb[d];
        yv[j] = y;
        ss += y * y;
    }
    const int lane = tid & 63, wid = tid >> 6;
#pragma unroll
    for (int off = 32; off; off >>= 1) ss += __shfl_xor(ss, off);
    if (lane == 0) red[wid] = ss;
    __syncthreads();
    if (tid == 0) {
        float s4 = red[0] + red[1] + red[2] + red[3];
        red[4] = 1.0f / sqrtf(s4 * (1.0f / 5120.f) + 1e-8f);
    }
    __syncthreads();
    const float inv = red[4];

    const size_t rowbase = (size_t)(t >> 7) * 80 * 8192 + (size_t)(t & 127) * 64;
    const int xr = (t & 7) << 3;

    float r0 = 0.f, r1 = 0.f, r2 = 0.f, r3 = 0.f;
#pragma unroll
    for (int j = 0; j < 20; ++j) {
        int k = tid + j * 256;
        float nv = yv[j] * inv * rms_w[k];
        nbf[rowbase + (size_t)(k >> 6) * 8192 + ((k & 63) ^ xr)] = f2bf(nv);
        r0 += nv * router_w[k];
        r1 += nv * router_w[IND + k];
        r2 += nv * router_w[2 * IND + k];
        r3 += nv * router_w[3 * IND + k];
    }
#pragma unroll
    for (int off = 32; off; off >>= 1) {
        r0 += __shfl_xor(r0, off); r1 += __shfl_xor(r1, off);
        r2 += __shfl_xor(r2, off); r3 += __shfl_xor(r3, off);
    }
    if (lane == 0) { rred[wid*4+0]=r0; rred[wid*4+1]=r1; rred[wid*4+2]=r2; rred[wid*4+3]=r3; }
    __syncthreads();
    if (tid == 0) {
        float p[4];
#pragma unroll
        for (int e = 0; e < 4; ++e) {
            float lg = rred[e] + rred[4+e] + rred[8+e] + rred[12+e];
            p[e] = 1.0f / (1.0f + expf(-lg));
        }
        int i1 = 0;
        for (int e = 1; e < 4; ++e) if (p[e] > p[i1]) i1 = e;
        int i2 = (i1 == 0) ? 1 : 0;
        for (int e = 0; e < 4; ++e) if (e != i1 && p[e] > p[i2]) i2 = e;
        float wsum = p[i1] + p[i2] + 1e-6f;
        float c[4] = {0.f, 0.f, 0.f, 0.f};
        c[i1] = p[i1] / wsum;
        c[i2] = p[i2] / wsum;
        combine[t*4+0] = c[0]; combine[t*4+1] = c[1];
        combine[t*4+2] = c[2]; combine[t*4+3] = c[3];
    }
}

// ---------------- fp32 -> bf16 tiled+swizzled weight conversion ----------------
// src is [R][C] fp32 row-major. One block per 128x64 tile.
// dst tile index = (by + row_toff) * KT + (bx + k_toff); within-tile layout as above.
__global__ __launch_bounds__(256)
void convert_tiled(const float* __restrict__ src, short* __restrict__ dst,
                   int C, int KT, int row_toff, int k_toff)
{
    const int bx = blockIdx.x;   // k tile
    const int by = blockIdx.y;   // row tile
    short* tbase = dst + ((size_t)(by + row_toff) * KT + (bx + k_toff)) * 8192;
    const float* sbase = src + (size_t)by * 128 * C + (size_t)bx * 64;
#pragma unroll
    for (int it = 0; it < 4; ++it) {
        const int idx = it * 256 + threadIdx.x;   // 0..1023
        const int r = idx >> 3, ch = idx & 7;
        const float* s = sbase + (size_t)r * C + ch * 8;
        float4 a = *(const float4*)s;
        float4 b = *(const float4*)(s + 4);
        short8v o;
        o[0] = f2bf(a.x); o[1] = f2bf(a.y); o[2] = f2bf(a.z); o[3] = f2bf(a.w);
        o[4] = f2bf(b.x); o[5] = f2bf(b.y); o[6] = f2bf(b.z); o[7] = f2bf(b.w);
        *(short8v*)(tbase + r * 64 + ((ch ^ (r & 7)) << 3)) = o;
    }
}

// ---------------- GEMM (128x128, BK=64, tile-native operands) ----------------
// MODE 1: h = relu(n @ W1_all^T + b1); routed cols scaled by combine -> bf16 tiled
// MODE 2: partial out = h_scaled @ W2_seg^T (split-K over blockIdx.z) -> fp32
template<int MODE>
__global__ __launch_bounds__(256, 5)
void gemm_kernel(const short* __restrict__ A, const short* __restrict__ Bw,
                 const float* __restrict__ sb1, const float* __restrict__ eb1,
                 const float* __restrict__ combine,
                 short* __restrict__ Hout, float* __restrict__ Pout)
{
    constexpr int KT  = (MODE == 1) ? 80 : 160;   // k-tiles per row-block
    constexpr int NKT = (MODE == 1) ? 80 : 40;    // k-tiles this block processes
    __shared__ short As[8192];
    __shared__ short Bs[8192];
    const int tid  = threadIdx.x;
    const int lane = tid & 63;
    const int wid  = tid >> 6;
    const int wr   = wid >> 1, wc = wid & 1;
    const int kt0  = (MODE == 2) ? blockIdx.z * NKT : 0;

    const short* at = A  + ((size_t)blockIdx.y * KT + kt0) * 8192;
    const short* bt = Bw + ((size_t)blockIdx.x * KT + kt0) * 8192;

    floatx4 acc[4][4] = {};

    for (int kt = 0; kt < NKT; ++kt) {
#pragma unroll
        for (int i = 0; i < 4; ++i) {
            const int o = (i * 256 + tid) * 8;
            __builtin_amdgcn_global_load_lds(
                (const __attribute__((address_space(1))) void*)(at + o),
                (__attribute__((address_space(3))) void*)(As + o), 16, 0, 0);
            __builtin_amdgcn_global_load_lds(
                (const __attribute__((address_space(1))) void*)(bt + o),
                (__attribute__((address_space(3))) void*)(Bs + o), 16, 0, 0);
        }
        at += 8192; bt += 8192;
        __syncthreads();
#pragma unroll
        for (int kk = 0; kk < 2; ++kk) {
            short8v af[4], bfr[4];
#pragma unroll
            for (int m = 0; m < 4; ++m) {
                const int r = wr * 64 + m * 16 + (lane & 15);
                const int c = (kk * 32 + (lane >> 4) * 8) ^ ((r & 7) << 3);
                af[m] = *(const short8v*)(As + r * 64 + c);
            }
#pragma unroll
            for (int n = 0; n < 4; ++n) {
                const int r = wc * 64 + n * 16 + (lane & 15);
                const int c = (kk * 32 + (lane >> 4) * 8) ^ ((r & 7) << 3);
                bfr[n] = *(const short8v*)(Bs + r * 64 + c);
            }
#pragma unroll
            for (int m = 0; m < 4; ++m)
#pragma unroll
                for (int n = 0; n < 4; ++n)
                    acc[m][n] = __builtin_amdgcn_mfma_f32_16x16x32_bf16(
                        af[m], bfr[n], acc[m][n], 0, 0, 0);
        }
        __syncthreads();
    }

    const int m0 = blockIdx.y * 128;
    const int n0 = blockIdx.x * 128;
#pragma unroll
    for (int m = 0; m < 4; ++m) {
        const int rb = m0 + wr * 64 + m * 16 + ((lane >> 4) * 4);
#pragma unroll
        for (int n = 0; n < 4; ++n) {
            const int col = n0 + wc * 64 + n * 16 + (lane & 15);
#pragma unroll
            for (int r = 0; r < 4; ++r) {
                const int rowg = rb + r;
                float v = acc[m][n][r];
                if constexpr (MODE == 1) {
                    v += (col < 2048) ? sb1[col] : eb1[col - 2048];
                    v = fmaxf(v, 0.0f);
                    if (col >= 2048) v *= combine[rowg * 4 + ((col - 2048) >> 11)];
                    const size_t tb = ((size_t)(rowg >> 7) * 160 + (col >> 6)) * 8192;
                    Hout[tb + (size_t)(rowg & 127) * 64 + ((col & 63) ^ ((rowg & 7) << 3))] = f2bf(v);
                } else {
                    float* P = Pout + (size_t)blockIdx.z * (1024u * 2048u);
                    P[(size_t)rowg * 2048 + col] = v;
                }
            }
        }
    }
}

// ---------------- split-K reduce + bias ----------------
__global__ __launch_bounds__(256)
void reduce_kernel(const float* __restrict__ part, const float* __restrict__ sb2,
                   const float* __restrict__ eb2, const float* __restrict__ combine,
                   float* __restrict__ out)
{
    const int idx  = blockIdx.x * 256 + threadIdx.x;  // float4 index
    const int base = idx * 4;
    const int row  = base >> 11;
    const int col  = base & 2047;
    const size_t NP = 1024u * 2048u;
    float4 s0 = *(const float4*)(part + base);
    float4 s1 = *(const float4*)(part + NP + base);
    float4 s2 = *(const float4*)(part + 2 * NP + base);
    float4 s3 = *(const float4*)(part + 3 * NP + base);
    const float c0 = combine[row * 4 + 0], c1 = combine[row * 4 + 1];
    const float c2 = combine[row * 4 + 2], c3 = combine[row * 4 + 3];
    float4 o;
    float* op = (float*)&o;
    const float* p0 = (const float*)&s0; const float* p1 = (const float*)&s1;
    const float* p2 = (const float*)&s2; const float* p3 = (const float*)&s3;
#pragma unroll
    for (int j = 0; j < 4; ++j) {
        const int c = col + j;
        float b2 = sb2[c] + c0 * eb2[c] + c1 * eb2[2048 + c]
                 + c2 * eb2[4096 + c] + c3 * eb2[6144 + c];
        op[j] = p0[j] + p1[j] + p2[j] + p3[j] + b2;
    }
    *(float4*)(out + base) = o;
}

extern "C" void kernel_launch(void* const* d_in, const int* in_sizes, int n_in,
                              void* d_out, int out_size, void* d_ws, size_t ws_size,
                              hipStream_t stream)
{
    const float* x        = (const float*)d_in[0];
    const float* conv_w   = (const float*)d_in[1];
    const float* conv_b   = (const float*)d_in[2];
    const float* rms_w    = (const float*)d_in[3];
    const float* router_w = (const float*)d_in[4];
    const float* sw1      = (const float*)d_in[5];
    const float* sb1      = (const float*)d_in[6];
    const float* sw2      = (const float*)d_in[7];
    const float* sb2      = (const float*)d_in[8];
    const float* ew1      = (const float*)d_in[9];
    const float* eb1      = (const float*)d_in[10];
    const float* ew2      = (const float*)d_in[11];
    const float* eb2      = (const float*)d_in[12];
    float* out = (float*)d_out;

    char* ws = (char*)d_ws;
    short* nbf     = (short*)(ws);                    // 1024*5120*2   = 10,485,760
    short* hbf     = (short*)(ws + 10485760);         // 1024*10240*2  = 20,971,520
    short* w1b     = (short*)(ws + 31457280);         // 10240*5120*2  = 104,857,600
    float* part2   = (float*)(ws + 31457280);         // 4*1024*2048*4 = 33,554,432 (aliases w1b; stream-ordered safe)
    short* w2b     = (short*)(ws + 136314880);        // 2048*10240*2  = 41,943,040
    float* combine = (float*)(ws + 178257920);        // 1024*4*4      = 16,384

    pre_kernel<<<1024, 256, 0, stream>>>(x, conv_w, conv_b, rms_w, router_w, nbf, combine);

    // W1_all virtual [10240][5120]: shared rows 0..2047, expert e rows 2048+e*2048..
    convert_tiled<<<dim3(80, 16), 256, 0, stream>>>(sw1, w1b, 5120, 80, 0, 0);
    convert_tiled<<<dim3(80, 64), 256, 0, stream>>>(ew1, w1b, 5120, 80, 16, 0);
    // W2_all virtual [2048][10240]: k 0..2047 shared, then expert e at k-tiles 32+e*32
    convert_tiled<<<dim3(32, 16), 256, 0, stream>>>(sw2, w2b, 2048, 160, 0, 0);
    for (int e = 0; e < 4; ++e)
        convert_tiled<<<dim3(32, 16), 256, 0, stream>>>(
            ew2 + (size_t)e * 2048 * 2048, w2b, 2048, 160, 0, 32 + e * 32);

    gemm_kernel<1><<<dim3(80, 8), 256, 0, stream>>>(
        nbf, w1b, sb1, eb1, combine, hbf, nullptr);
    gemm_kernel<2><<<dim3(16, 8, 4), 256, 0, stream>>>(
        hbf, w2b, nullptr, nullptr, combine, nullptr, part2);

    reduce_kernel<<<2048, 256, 0, stream>>>(part2, sb2, eb2, combine, out);
}